// Round 5
// baseline (256.322 us; speedup 1.0000x reference)
//
#include <hip/hip_runtime.h>
#include <hip/hip_bf16.h>
#include <math.h>

// MultiSimilarityLoss on MI355X — R5: occupancy + launch-gap attack.
// R4 post-mortem: 2 waves/SIMD can't hide VALU dep-chains (52% VALUBusy,
// 65% combined util) and 5 dispatches cost ~26 µs of gaps.
// Changes: 512-thread blocks (8 waves 2x4, acc[4][2]) with
// __launch_bounds__(512,4) -> 4 waves/SIMD, 2 blocks/CU, grid 512
// co-resident; k_rows/k_fin folded into k_gemm<2> via threadfence+ticket
// last-block reduction; self-test hoisted off the epilogue for the 504/512
// non-diagonal blocks. XOR-swizzled LDS kept (R4: bank conflicts == 0).
// bf16-S numerics validated R3/R4 (absmax 0.0 vs threshold 4.75e-2).

namespace {

constexpr int Bsz = 8192;
constexpr int Dd  = 128;
constexpr float EPSv = 0.1f;

constexpr int BM = 128, BN = 128;
constexpr int NSPLIT = 8;
constexpr int COLS_PER_SPLIT = Bsz / NSPLIT;       // 1024
constexpr int CT_PER_SPLIT = COLS_PER_SPLIT / BN;  // 8
constexpr int NBLK_M = Bsz / BM;                   // 64
constexpr int NBLOCKS = NBLK_M * NSPLIT;           // 512

typedef __attribute__((ext_vector_type(8))) short short8;   // 8 bf16 = 4 VGPRs
typedef __attribute__((ext_vector_type(4))) float float4v;  // MFMA C/D

__device__ inline void async_ld16(const void* g, void* l) {
  __builtin_amdgcn_global_load_lds(
      (const __attribute__((address_space(1))) void*)g,
      (__attribute__((address_space(3))) void*)l, 16, 0, 0);
}

// Stage a 128x128 bf16 slab into LDS with XOR swizzle (512 threads).
// Physical 16B chunk P = i*512+tid holds logical (m=P>>4, c=(P&15)^(m&15)).
__device__ inline void stage_slab(const ushort* __restrict__ src, int baserow,
                                  short* __restrict__ dst, int tid) {
#pragma unroll
  for (int i = 0; i < 4; ++i) {
    const int P = i * 512 + tid;
    const int m = P >> 4;
    const int c = (P & 15) ^ (m & 15);
    async_ld16(src + (size_t)(baserow + m) * Dd + c * 8, dst + P * 8);
  }
}

// cast x (fp32) to bf16; zero the grid ticket (ws is poisoned 0xAA)
__global__ __launch_bounds__(256)
void k_split(const float* __restrict__ x, ushort* __restrict__ xh,
             int* __restrict__ ticket) {
  const int i = (blockIdx.x * 256 + threadIdx.x) * 4;
  if (i == 0) *ticket = 0;
  const float4 v = *reinterpret_cast<const float4*>(x + i);
  const float f[4] = {v.x, v.y, v.z, v.w};
  ushort4 h;
  ushort* hp = &h.x;
#pragma unroll
  for (int r = 0; r < 4; ++r) {
    __hip_bfloat16 hb = __float2bfloat16(f[r]);
    ushort hu;
    __builtin_memcpy(&hu, &hb, 2);
    hp[r] = hu;
  }
  *reinterpret_cast<ushort4*>(xh + i) = h;
}

// PASS=1: out0/out1 = per-split partial min_pos / max_neg.
// PASS=2: in0/in1 = pMin/pMax partials (reduced in prologue);
//         out0/out1 = partial pos_sum/neg_sum; last block writes final loss.
template <int PASS>
__global__ __launch_bounds__(512, 4)
void k_gemm(const ushort* __restrict__ xh, const int* __restrict__ y,
            const float* __restrict__ in0, const float* __restrict__ in1,
            float* __restrict__ out0, float* __restrict__ out1,
            int* __restrict__ ticket, float* __restrict__ outF) {
  __shared__ __align__(16) short sA[BM * Dd];  // 32 KB
  __shared__ __align__(16) short sB[BN * Dd];  // 32 KB
  __shared__ int yA[BM], yB[BN];
  __shared__ float red0[BM][4], red1[BM][4];   // 2 KB each
  __shared__ float rlo[BM], rhi[BM];

  const int tid  = threadIdx.x;
  const int lane = tid & 63;
  const int wave = tid >> 6;                 // 0..7
  const int wm = wave >> 2, wn = wave & 3;   // 2x4 wave grid: 64x32 per wave
  const int q   = lane >> 4;                 // row-quad selector
  const int c16 = lane & 15;                 // col within 16-tile
  const int rowbase = blockIdx.x * BM;
  const int split   = blockIdx.y;
  const int col0    = split * COLS_PER_SPLIT;

  if (tid < BM) {
    yA[tid] = y[rowbase + tid];
    if (PASS == 2) {  // fold k_thresh: reduce row thresholds for our rows
      float mn = INFINITY, mx = -INFINITY;
#pragma unroll
      for (int s = 0; s < NSPLIT; ++s) {
        mn = fminf(mn, in0[s * Bsz + rowbase + tid]);
        mx = fmaxf(mx, in1[s * Bsz + rowbase + tid]);
      }
      rlo[tid] = mn;
      rhi[tid] = mx;
    }
  }
  if (tid < BN) yB[tid] = y[col0 + tid];

  stage_slab(xh, rowbase, sA, tid);
  stage_slab(xh, col0, sB, tid);

  // register carries (per-row mt x r), reduced over nt/ct
  float a0[4][4], a1[4][4];  // PASS1: mn/mx ; PASS2: psum/nsum
#pragma unroll
  for (int mt = 0; mt < 4; ++mt)
#pragma unroll
    for (int r = 0; r < 4; ++r) {
      a0[mt][r] = (PASS == 1) ? INFINITY : 0.f;
      a1[mt][r] = (PASS == 1) ? -INFINITY : 0.f;
    }

  for (int ct = 0; ct < CT_PER_SPLIT; ++ct) {
    const int colbase = col0 + ct * BN;
    __syncthreads();  // drains stage of sB(ct) (+sA on ct=0), yB(ct)

    float4v acc[4][2];
#pragma unroll
    for (int mt = 0; mt < 4; ++mt)
#pragma unroll
      for (int nt = 0; nt < 2; ++nt) acc[mt][nt] = 0.f;

#pragma unroll
    for (int kk = 0; kk < 4; ++kk) {
      short8 ah[4], bh[2];
#pragma unroll
      for (int t = 0; t < 4; ++t) {
        const int pc = ((kk << 2) | q) ^ c16;  // physical chunk (xor swizzle)
        ah[t] = *reinterpret_cast<const short8*>(
            sA + (wm * 64 + t * 16 + c16) * Dd + pc * 8);
        if (t < 2)
          bh[t] = *reinterpret_cast<const short8*>(
              sB + (wn * 32 + t * 16 + c16) * Dd + pc * 8);
      }
#pragma unroll
      for (int mt = 0; mt < 4; ++mt)
#pragma unroll
        for (int nt = 0; nt < 2; ++nt)
          acc[mt][nt] = __builtin_amdgcn_mfma_f32_16x16x32_bf16(
              ah[mt], bh[nt], acc[mt][nt], 0, 0, 0);
    }

    // capture labels before yB is overwritten by the next stage
    int yy[2];
#pragma unroll
    for (int nt = 0; nt < 2; ++nt) yy[nt] = yB[wn * 32 + nt * 16 + c16];

    if (ct < CT_PER_SPLIT - 1) {
      __syncthreads();  // all waves done reading sB(ct)/yB(ct)
      stage_slab(xh, colbase + BN, sB, tid);  // async; drained at loop top
      if (tid < BN) yB[tid] = y[colbase + BN + tid];
    }

    // epilogue (pure VALU) overlaps the in-flight staging.
    // C/D layout col=lane&15, row=(lane>>4)*4+reg  [m89; R2-R4 absmax 0.0]
    const bool diag = (colbase == rowbase);  // self-pairs possible only here
#pragma unroll
    for (int mt = 0; mt < 4; ++mt) {
#pragma unroll
      for (int r = 0; r < 4; ++r) {
        const int rloc = wm * 64 + mt * 16 + q * 4 + r;
        const int yi = yA[rloc];
        if (PASS == 1) {
          float mn = a0[mt][r], mx = a1[mt][r];
#pragma unroll
          for (int nt = 0; nt < 2; ++nt) {
            const float s = acc[mt][nt][r];
            const bool same = (yi == yy[nt]);
            const bool self =
                diag && (rloc == wn * 32 + nt * 16 + c16);
            mn = fminf(mn, (same && !self) ? s : INFINITY);
            mx = fmaxf(mx, same ? -INFINITY : s);
          }
          a0[mt][r] = mn;
          a1[mt][r] = mx;
        } else {
          float psum = a0[mt][r], nsum = a1[mt][r];
          const float rmn = rlo[rloc], rmx = rhi[rloc];
#pragma unroll
          for (int nt = 0; nt < 2; ++nt) {
            const float s = acc[mt][nt][r];
            const bool same = (yi == yy[nt]);
            const bool self =
                diag && (rloc == wn * 32 + nt * 16 + c16);
            // exp(beta*(s-1)) = e^-50 * e^(50 s): accumulate unscaled
            // e^(50 s) (>= e^-50, never 0 -> nsum>0 <=> any neg kept).
            const float e = __expf(same ? (-2.f * s) : (50.f * s));
            if (!same && (s + EPSv > rmn)) nsum += e;
            if (same && !self && (s - EPSv < rmx)) psum += e;
          }
          a0[mt][r] = psum;
          a1[mt][r] = nsum;
        }
      }
    }
  }

  // cross-lane reduce; (rloc, wn) has a unique writer lane
#pragma unroll
  for (int mt = 0; mt < 4; ++mt) {
#pragma unroll
    for (int r = 0; r < 4; ++r) {
      float v0 = a0[mt][r], v1 = a1[mt][r];
#pragma unroll
      for (int d = 1; d < 16; d <<= 1) {
        if (PASS == 1) {
          v0 = fminf(v0, __shfl_xor(v0, d, 64));
          v1 = fmaxf(v1, __shfl_xor(v1, d, 64));
        } else {
          v0 += __shfl_xor(v0, d, 64);
          v1 += __shfl_xor(v1, d, 64);
        }
      }
      if (c16 == 0) {
        const int rloc = wm * 64 + mt * 16 + q * 4 + r;
        red0[rloc][wn] = v0;
        red1[rloc][wn] = v1;
      }
    }
  }

  __syncthreads();
  if (tid < BM) {
    const int o = split * Bsz + rowbase + tid;
    if (PASS == 1) {
      out0[o] = fminf(fminf(red0[tid][0], red0[tid][1]),
                      fminf(red0[tid][2], red0[tid][3]));
      out1[o] = fmaxf(fmaxf(red1[tid][0], red1[tid][1]),
                      fmaxf(red1[tid][2], red1[tid][3]));
    } else {
      out0[o] = (red0[tid][0] + red0[tid][1]) + (red0[tid][2] + red0[tid][3]);
      out1[o] = (red1[tid][0] + red1[tid][1]) + (red1[tid][2] + red1[tid][3]);
    }
  }

  if (PASS == 2) {
    // last-block grid reduction (rocPRIM decoupled-lookback pattern):
    // release partials, take a ticket; block 511 acquires + finalizes.
    __threadfence();
    __shared__ int lastFlag;
    if (tid == 0) lastFlag = (atomicAdd(ticket, 1) == NBLOCKS - 1);
    __syncthreads();
    if (lastFlag) {
      __threadfence();
      float ls = 0.f, lc = 0.f;
      for (int r = tid; r < Bsz; r += 512) {
        float ps = 0.f, ns = 0.f;
#pragma unroll
        for (int s = 0; s < NSPLIT; ++s) {
          ps += out0[s * Bsz + r];
          ns += out1[s * Bsz + r];
        }
        if (ps > 0.f && ns > 0.f) {
          const float E2   = 7.38905609893065f;       // e^{+alpha*lamda}
          const float EM50 = 1.928749847963918e-22f;  // e^{-beta*lamda}
          ls += 0.5f * log1pf(ps * E2) + 0.02f * log1pf(ns * EM50);
          lc += 1.f;
        }
      }
#pragma unroll
      for (int d = 1; d < 64; d <<= 1) {
        ls += __shfl_xor(ls, d, 64);
        lc += __shfl_xor(lc, d, 64);
      }
      float* rbuf = &red0[0][0];
      float* cbuf = &red1[0][0];
      if (lane == 0) { rbuf[wave] = ls; cbuf[wave] = lc; }
      __syncthreads();
      if (tid == 0) {
        float S = 0.f, C = 0.f;
#pragma unroll
        for (int w = 0; w < 8; ++w) { S += rbuf[w]; C += cbuf[w]; }
        outF[0] = (C > 0.f) ? S / C : 0.f;
      }
    }
  }
}

}  // namespace

extern "C" void kernel_launch(void* const* d_in, const int* in_sizes, int n_in,
                              void* d_out, int out_size, void* d_ws, size_t ws_size,
                              hipStream_t stream) {
  const float* x = (const float*)d_in[0];
  const int*   y = (const int*)d_in[1];
  float* out = (float*)d_out;

  // workspace layout
  ushort* xh  = (ushort*)d_ws;                      // [Bsz*Dd] bf16 (2 MB)
  float* pMin = (float*)(xh + (size_t)Bsz * Dd);    // [NSPLIT][Bsz]
  float* pMax = pMin + NSPLIT * Bsz;
  float* pPos = pMax + NSPLIT * Bsz;
  float* pNeg = pPos + NSPLIT * Bsz;
  int* ticket = (int*)(pNeg + NSPLIT * Bsz);        // [1]

  k_split<<<dim3((Bsz * Dd) / (256 * 4)), dim3(256), 0, stream>>>(x, xh, ticket);

  dim3 grid(NBLK_M, NSPLIT), blk(512);
  k_gemm<1><<<grid, blk, 0, stream>>>(xh, y, nullptr, nullptr, pMin, pMax,
                                      nullptr, nullptr);
  k_gemm<2><<<grid, blk, 0, stream>>>(xh, y, pMin, pMax, pPos, pNeg,
                                      ticket, out);
}